// Round 2
// baseline (1395.421 us; speedup 1.0000x reference)
//
#include <hip/hip_runtime.h>
#include <math.h>

// DIN-style fused kernel, fp32 correctness-first version.
// One block per batch row. Key simplifications:
//   pred[b] = sum_s attn_w[s]*(hist_s . u) + sum_s hvr[s]*(hist_s . targ),  u = Wv^T targ
//   scores[j] += q[f/200] * k[s,h]  where f = s*128+h, j = f%200   (faithful reshape bug)
// so neither k nor v is ever materialized in global memory.

#define BB 2048
#define HH 200
#define EE 128

__global__ __launch_bounds__(512) void fused_din(
    const int* __restrict__ history,        // [B,H]
    const int* __restrict__ target,         // [B]
    const int* __restrict__ history_region, // [B,H]
    const int* __restrict__ target_region,  // [B]
    const float* __restrict__ hvr,          // [H]
    const float* __restrict__ embT,         // [100000,64]
    const float* __restrict__ embR,         // [1000,64]
    const float* __restrict__ Wq,           // [128,128]
    const float* __restrict__ Wk,           // [128,128]
    const float* __restrict__ Wv,           // [128,128]
    float* __restrict__ out)                // [B]
{
    const int b   = blockIdx.x;
    const int tid = threadIdx.x;

    // 200*132*4 = 105.6 KB (rows padded to 132 floats: keeps float4 alignment,
    // breaks power-of-2 stride for the per-lane row reads)
    __shared__ float s_hist[HH][132];
    __shared__ float s_targ[EE];
    __shared__ float s_q[EE];
    __shared__ float s_u[EE];
    __shared__ float s_scores[HH];
    __shared__ float s_hdot[HH];
    __shared__ float s_tdot[HH];
    __shared__ int   s_uh[HH];
    __shared__ float s_red[8];
    __shared__ float s_total;

    const int tgt_i = target[b];

    // ---- Phase A0: target embedding -> s_targ; zero accumulators; stage Wq ----
    if (tid < 16) {
        float4 v = *(const float4*)(embT + (size_t)tgt_i * 64 + tid * 4);
        *(float4*)&s_targ[tid * 4] = v;
    } else if (tid < 32) {
        int j = tid - 16;
        int tr_i = target_region[b];
        float4 v = *(const float4*)(embR + (size_t)tr_i * 64 + j * 4);
        *(float4*)&s_targ[64 + j * 4] = v;
    }
    if (tid < HH) { s_scores[tid] = 0.f; s_hdot[tid] = 0.f; s_tdot[tid] = 0.f; }

    // stage Wq (padded rows of 132) into the s_hist region before hist overwrites it
    float* s_wq = &s_hist[0][0];
    for (int i = tid; i < 128 * 32; i += 512) {
        int h = i >> 5;
        int j = i & 31;
        float4 v = *(const float4*)(Wq + h * 128 + j * 4);
        *(float4*)(s_wq + h * 132 + j * 4) = v;
    }
    __syncthreads();

    // ---- Phase A1: q[h] = Wq[h,:].targ  (tid<128) ; u[e] = sum_f targ[f]*Wv[f,e] (tid 128..255) ----
    if (tid < 128) {
        float acc = 0.f;
        #pragma unroll
        for (int e = 0; e < 128; e += 4) {
            float4 w = *(const float4*)(s_wq + tid * 132 + e);
            acc += w.x * s_targ[e] + w.y * s_targ[e + 1] + w.z * s_targ[e + 2] + w.w * s_targ[e + 3];
        }
        s_q[tid] = acc;
    } else if (tid < 256) {
        int e = tid - 128;
        float acc = 0.f;
        for (int f = 0; f < 128; f++)           // coalesced across lanes (consecutive e)
            acc += s_targ[f] * Wv[f * 128 + e];
        s_u[e] = acc;
    }

    // ---- Wk fragment -> registers (global reads, L2-hot; independent of LDS) ----
    const int hp = tid & 127;   // which Wk row / k-column this thread owns
    const int eq = tid >> 7;    // which e-quarter (0..3) of the dot product
    float wk[32];
    {
        const float* wkrow = Wk + hp * 128 + eq * 32;
        #pragma unroll
        for (int i = 0; i < 8; i++) {
            float4 v = *(const float4*)(wkrow + i * 4);
            wk[i * 4 + 0] = v.x; wk[i * 4 + 1] = v.y;
            wk[i * 4 + 2] = v.z; wk[i * 4 + 3] = v.w;
        }
    }
    __syncthreads();   // q,u done; s_wq region free for hist

    // ---- Phase B: gather history embeddings into LDS + hdot/tdot partials ----
    // 16 threads per row (each loads one float4 from each table), 32 rows/iter
    for (int base = 0; base < HH; base += 32) {
        int r = base + (tid >> 4);
        int j = tid & 15;
        if (r < HH) {
            int ih = history[b * HH + r];
            int ir = history_region[b * HH + r];
            float4 t4 = *(const float4*)(embT + (size_t)ih * 64 + j * 4);
            float4 r4 = *(const float4*)(embR + (size_t)ir * 64 + j * 4);
            *(float4*)&s_hist[r][j * 4]      = t4;
            *(float4*)&s_hist[r][64 + j * 4] = r4;
            if (j == 0) s_uh[r] = ih;
            float hp_ = t4.x * s_u[j*4]   + t4.y * s_u[j*4+1]   + t4.z * s_u[j*4+2]   + t4.w * s_u[j*4+3]
                      + r4.x * s_u[64+j*4] + r4.y * s_u[64+j*4+1] + r4.z * s_u[64+j*4+2] + r4.w * s_u[64+j*4+3];
            float tp_ = t4.x * s_targ[j*4]   + t4.y * s_targ[j*4+1]   + t4.z * s_targ[j*4+2]   + t4.w * s_targ[j*4+3]
                      + r4.x * s_targ[64+j*4] + r4.y * s_targ[64+j*4+1] + r4.z * s_targ[64+j*4+2] + r4.w * s_targ[64+j*4+3];
            atomicAdd(&s_hdot[r], hp_);
            atomicAdd(&s_tdot[r], tp_);
        }
    }
    __syncthreads();

    // ---- Phase C: k[s,hp] partial over my e-quarter, scattered into scores ----
    // hist reads are wave-uniform (broadcast, conflict-free); scatter addresses
    // are 64 consecutive values mod 200 -> distinct, ~2-way bank (free).
    for (int s = 0; s < HH; s++) {
        const float* hrow = &s_hist[s][eq * 32];
        float acc = 0.f;
        #pragma unroll
        for (int i = 0; i < 8; i++) {
            float4 h4 = *(const float4*)(hrow + i * 4);
            acc += h4.x * wk[i*4] + h4.y * wk[i*4+1] + h4.z * wk[i*4+2] + h4.w * wk[i*4+3];
        }
        int f  = s * 128 + hp;
        int fd = f / 200;              // magic-mul div
        int fm = f - fd * 200;
        atomicAdd(&s_scores[fm], s_q[fd] * acc);
    }
    __syncthreads();

    // ---- Phase D: masked exp, beta=0.5 normalization, final reduce, sigmoid ----
    float ev = 0.f;
    if (tid < HH) {
        float sc = s_scores[tid] * 0.088388347648318447f;  // 1/sqrt(128)
        ev = (s_uh[tid] != tgt_i) ? expf(sc) : 0.f;
    }
    float sum = ev;
    #pragma unroll
    for (int m = 1; m < 64; m <<= 1) sum += __shfl_xor(sum, m, 64);
    int wid = tid >> 6;
    if ((tid & 63) == 0) s_red[wid] = sum;
    __syncthreads();
    if (tid == 0) {
        float t = 0.f;
        #pragma unroll
        for (int w = 0; w < 8; w++) t += s_red[w];
        s_total = t;
    }
    __syncthreads();

    float pv = 0.f;
    if (tid < HH) {
        float attn = ev * rsqrtf(s_total);          // exp_A / sum^0.5
        pv = attn * s_hdot[tid] + hvr[tid] * s_tdot[tid];
    }
    float psum = pv;
    #pragma unroll
    for (int m = 1; m < 64; m <<= 1) psum += __shfl_xor(psum, m, 64);
    if ((tid & 63) == 0) s_red[wid] = psum;
    __syncthreads();
    if (tid == 0) {
        float pred = 0.f;
        #pragma unroll
        for (int w = 0; w < 8; w++) pred += s_red[w];
        out[b] = 1.0f / (1.0f + expf(-pred));
    }
}

extern "C" void kernel_launch(void* const* d_in, const int* in_sizes, int n_in,
                              void* d_out, int out_size, void* d_ws, size_t ws_size,
                              hipStream_t stream) {
    const int*   history = (const int*)d_in[0];
    const int*   target  = (const int*)d_in[1];
    const int*   hregion = (const int*)d_in[2];
    const int*   tregion = (const int*)d_in[3];
    const float* hvrate  = (const float*)d_in[4];
    const float* embT    = (const float*)d_in[5];
    const float* embR    = (const float*)d_in[6];
    const float* Wq      = (const float*)d_in[7];
    const float* Wk      = (const float*)d_in[8];
    const float* Wv      = (const float*)d_in[9];
    float* outp = (float*)d_out;

    dim3 grid(BB), block(512);
    hipLaunchKernelGGL(fused_din, grid, block, 0, stream,
                       history, target, hregion, tregion, hvrate,
                       embT, embR, Wq, Wk, Wv, outp);
}

// Round 3
// 321.453 us; speedup vs baseline: 4.3410x; 4.3410x over previous
//
#include <hip/hip_runtime.h>
#include <math.h>

// DIN-style fused kernel, round 3: bf16 MFMA for the K-projection.
//   pred[b] = sum_s attn_w[s]*(hist_s . u) + sum_s hvr[s]*(hist_s . targ),  u = Wv^T targ
//   scores[f%200] += q[f/200] * k[s,h],  f = s*128+h   (faithful reshape bug)
// One block per batch row, 256 threads (4 waves), hist processed in two
// 100-row halves staged as bf16 in LDS (~36 KB -> 4 blocks/CU).

#define BB 2048
#define HH 200
#define EE 128
#define HALF 100
#define PITCH 136   // bf16 elems/row: 272 B, 16B-aligned, 4-bank row skew

typedef float fp32x4 __attribute__((ext_vector_type(4)));
typedef short bf16x8 __attribute__((ext_vector_type(8)));

static __device__ __forceinline__ unsigned short f2bf(float x) {
    unsigned u = __builtin_bit_cast(unsigned, x);
    unsigned r = (u + 0x7FFFu + ((u >> 16) & 1u)) >> 16;   // RNE
    return (unsigned short)r;
}
static __device__ __forceinline__ float bf2f(short v) {
    unsigned u = ((unsigned)(unsigned short)v) << 16;
    return __builtin_bit_cast(float, u);
}

__global__ __launch_bounds__(256, 4) void fused_din_mfma(
    const int* __restrict__ history,        // [B,H]
    const int* __restrict__ target,         // [B]
    const int* __restrict__ history_region, // [B,H]
    const int* __restrict__ target_region,  // [B]
    const float* __restrict__ hvr,          // [H]
    const float* __restrict__ embT,         // [100000,64]
    const float* __restrict__ embR,         // [1000,64]
    const float* __restrict__ Wq,           // [128,128]
    const float* __restrict__ Wk,           // [128,128]
    const float* __restrict__ Wv,           // [128,128]
    float* __restrict__ out)                // [B]
{
    __shared__ unsigned short s_hist[112][PITCH];   // 112 rows: m-tile pad (rows >=100 garbage, scatter-predicated)
    __shared__ float s_targ[EE];
    __shared__ float s_q[EE];
    __shared__ float s_u[EE];
    __shared__ float s_scores[HH];
    __shared__ float s_hdot[HH];
    __shared__ float s_tdot[HH];
    __shared__ int   s_uh[HH];
    __shared__ int   s_hr[HH];
    __shared__ float s_red[4];
    __shared__ float s_total;

    const int b    = blockIdx.x;
    const int tid  = threadIdx.x;
    const int lane = tid & 63;
    const int w    = tid >> 6;
    const int tgt  = target[b];

    // ---- Wk B-fragments -> registers (global, L2-hot; no LDS dependency) ----
    // wave w owns output columns h in [32w, 32w+32): 2 n-tiles x 4 k-chunks.
    bf16x8 wkf[2][4];
    {
        const int hrow = 32 * w + (lane & 15);
        const int e0   = 8 * (lane >> 4);
        #pragma unroll
        for (int nt = 0; nt < 2; nt++)
            #pragma unroll
            for (int kc = 0; kc < 4; kc++) {
                const float* p = Wk + (size_t)(hrow + 16 * nt) * EE + 32 * kc + e0;
                float4 x = *(const float4*)p;
                float4 y = *(const float4*)(p + 4);
                bf16x8 f;
                f[0] = (short)f2bf(x.x); f[1] = (short)f2bf(x.y);
                f[2] = (short)f2bf(x.z); f[3] = (short)f2bf(x.w);
                f[4] = (short)f2bf(y.x); f[5] = (short)f2bf(y.y);
                f[6] = (short)f2bf(y.z); f[7] = (short)f2bf(y.w);
                wkf[nt][kc] = f;
            }
    }

    // ---- Phase 0: target embedding, ids, zero scores ----
    if (tid < 16) {
        float4 v = *(const float4*)(embT + (size_t)tgt * 64 + tid * 4);
        *(float4*)&s_targ[tid * 4] = v;
    } else if (tid < 32) {
        int j = tid - 16;
        float4 v = *(const float4*)(embR + (size_t)target_region[b] * 64 + j * 4);
        *(float4*)&s_targ[64 + j * 4] = v;
    }
    if (tid < HH) {
        s_scores[tid] = 0.f;
        s_uh[tid] = history[b * HH + tid];
        s_hr[tid] = history_region[b * HH + tid];
    }
    __syncthreads();

    // ---- Phase 1: u (tid<128) and q (tid>=128) ----
    if (tid < 128) {
        // u[e] = sum_f targ[f] * Wv[f,e]  -- lane-coalesced column reads
        const int e = tid;
        float a0 = 0.f, a1 = 0.f, a2 = 0.f, a3 = 0.f;
        #pragma unroll 4
        for (int f = 0; f < 128; f += 4) {
            a0 += s_targ[f]     * Wv[(size_t)f * EE + e];
            a1 += s_targ[f + 1] * Wv[(size_t)(f + 1) * EE + e];
            a2 += s_targ[f + 2] * Wv[(size_t)(f + 2) * EE + e];
            a3 += s_targ[f + 3] * Wv[(size_t)(f + 3) * EE + e];
        }
        s_u[e] = (a0 + a1) + (a2 + a3);
    } else {
        // q[h] = Wq[h,:] . targ  -- coalesced float4 chunks + 32-lane butterfly
        const int t = tid - 128;                 // 0..127
        const float4* Wq4 = (const float4*)Wq;
        const int colg = (t & 31) * 4;
        const float c0 = s_targ[colg], c1 = s_targ[colg + 1];
        const float c2 = s_targ[colg + 2], c3 = s_targ[colg + 3];
        #pragma unroll 4
        for (int k = 0; k < 32; k++) {
            float4 v = Wq4[t + 128 * k];
            float p = v.x * c0 + v.y * c1 + v.z * c2 + v.w * c3;
            p += __shfl_xor(p, 1, 64);
            p += __shfl_xor(p, 2, 64);
            p += __shfl_xor(p, 4, 64);
            p += __shfl_xor(p, 8, 64);
            p += __shfl_xor(p, 16, 64);
            if ((lane & 31) == 0) s_q[4 * k + (t >> 5)] = p;
        }
    }
    __syncthreads();

    // ---- Half loop: gather 100 rows -> bf16 LDS, hdot/tdot, MFMA + scatter ----
    for (int half = 0; half < 2; half++) {
        // gather: 16 lanes per row, float4 from each table, convert to bf16
        for (int base = 0; base < HALF; base += 16) {
            int r = base + (tid >> 4);
            int j = tid & 15;
            if (r < HALF) {
                int rg = half * HALF + r;
                int ih = s_uh[rg];
                int ir = s_hr[rg];
                float4 t4 = *(const float4*)(embT + (size_t)ih * 64 + j * 4);
                float4 r4 = *(const float4*)(embR + (size_t)ir * 64 + j * 4);
                ushort4 pt, pr;
                pt.x = f2bf(t4.x); pt.y = f2bf(t4.y); pt.z = f2bf(t4.z); pt.w = f2bf(t4.w);
                pr.x = f2bf(r4.x); pr.y = f2bf(r4.y); pr.z = f2bf(r4.z); pr.w = f2bf(r4.w);
                *(ushort4*)&s_hist[r][j * 4]      = pt;
                *(ushort4*)&s_hist[r][64 + j * 4] = pr;
            }
        }
        __syncthreads();

        // hdot/tdot: one thread per row, direct store (single writer)
        if (tid < HALF) {
            float hd = 0.f, td = 0.f;
            #pragma unroll
            for (int c = 0; c < 16; c++) {
                bf16x8 hv = *(const bf16x8*)&s_hist[tid][c * 8];
                #pragma unroll
                for (int j = 0; j < 8; j++) {
                    float hf = bf2f(hv[j]);
                    hd += hf * s_u[c * 8 + j];
                    td += hf * s_targ[c * 8 + j];
                }
            }
            s_hdot[half * HALF + tid] = hd;
            s_tdot[half * HALF + tid] = td;
        }

        // MFMA: 7 m-tiles x (2 n-tiles x 4 k-chunks), then scatter scores
        const int h0 = 32 * w + (lane & 15);
        const int e0 = 8 * (lane >> 4);
        for (int mt = 0; mt < 7; mt++) {
            const int m0 = mt * 16;
            const int arow = m0 + (lane & 15);
            bf16x8 a0 = *(const bf16x8*)&s_hist[arow][e0];
            bf16x8 a1 = *(const bf16x8*)&s_hist[arow][32 + e0];
            bf16x8 a2 = *(const bf16x8*)&s_hist[arow][64 + e0];
            bf16x8 a3 = *(const bf16x8*)&s_hist[arow][96 + e0];
            fp32x4 acc0 = {0.f, 0.f, 0.f, 0.f};
            fp32x4 acc1 = {0.f, 0.f, 0.f, 0.f};
            acc0 = __builtin_amdgcn_mfma_f32_16x16x32_bf16(a0, wkf[0][0], acc0, 0, 0, 0);
            acc1 = __builtin_amdgcn_mfma_f32_16x16x32_bf16(a0, wkf[1][0], acc1, 0, 0, 0);
            acc0 = __builtin_amdgcn_mfma_f32_16x16x32_bf16(a1, wkf[0][1], acc0, 0, 0, 0);
            acc1 = __builtin_amdgcn_mfma_f32_16x16x32_bf16(a1, wkf[1][1], acc1, 0, 0, 0);
            acc0 = __builtin_amdgcn_mfma_f32_16x16x32_bf16(a2, wkf[0][2], acc0, 0, 0, 0);
            acc1 = __builtin_amdgcn_mfma_f32_16x16x32_bf16(a2, wkf[1][2], acc1, 0, 0, 0);
            acc0 = __builtin_amdgcn_mfma_f32_16x16x32_bf16(a3, wkf[0][3], acc0, 0, 0, 0);
            acc1 = __builtin_amdgcn_mfma_f32_16x16x32_bf16(a3, wkf[1][3], acc1, 0, 0, 0);

            const int slbase = m0 + 4 * (lane >> 4);
            #pragma unroll
            for (int r = 0; r < 4; r++) {
                int sl = slbase + r;
                if (sl < HALF) {
                    unsigned f = (unsigned)((half * HALF + sl) * EE + h0);
                    unsigned fd = f / 200u;
                    unsigned fm = f - fd * 200u;
                    atomicAdd(&s_scores[fm], s_q[fd] * acc0[r]);
                    unsigned f2 = f + 16u;
                    unsigned fd2 = f2 / 200u;
                    unsigned fm2 = f2 - fd2 * 200u;
                    atomicAdd(&s_scores[fm2], s_q[fd2] * acc1[r]);
                }
            }
        }
        __syncthreads();   // scores/hdot done; s_hist reusable next half
    }

    // ---- Final: masked exp, beta=0.5 norm, pred, sigmoid ----
    float ev = 0.f;
    if (tid < HH) {
        float sc = s_scores[tid] * 0.088388347648318447f;   // 1/sqrt(128)
        ev = (s_uh[tid] != tgt) ? expf(sc) : 0.f;
    }
    float sum = ev;
    #pragma unroll
    for (int m = 1; m < 64; m <<= 1) sum += __shfl_xor(sum, m, 64);
    if (lane == 0) s_red[w] = sum;
    __syncthreads();
    if (tid == 0) s_total = (s_red[0] + s_red[1]) + (s_red[2] + s_red[3]);
    __syncthreads();

    float pv = 0.f;
    if (tid < HH) {
        float attn = ev * rsqrtf(s_total);
        pv = attn * s_hdot[tid] + hvr[tid] * s_tdot[tid];
    }
    float ps = pv;
    #pragma unroll
    for (int m = 1; m < 64; m <<= 1) ps += __shfl_xor(ps, m, 64);
    if (lane == 0) s_red[w] = ps;
    __syncthreads();
    if (tid == 0) {
        float pred = (s_red[0] + s_red[1]) + (s_red[2] + s_red[3]);
        out[b] = 1.0f / (1.0f + expf(-pred));
    }
}

extern "C" void kernel_launch(void* const* d_in, const int* in_sizes, int n_in,
                              void* d_out, int out_size, void* d_ws, size_t ws_size,
                              hipStream_t stream) {
    const int*   history = (const int*)d_in[0];
    const int*   target  = (const int*)d_in[1];
    const int*   hregion = (const int*)d_in[2];
    const int*   tregion = (const int*)d_in[3];
    const float* hvrate  = (const float*)d_in[4];
    const float* embT    = (const float*)d_in[5];
    const float* embR    = (const float*)d_in[6];
    const float* Wq      = (const float*)d_in[7];
    const float* Wk      = (const float*)d_in[8];
    const float* Wv      = (const float*)d_in[9];
    float* outp = (float*)d_out;

    dim3 grid(BB), block(256);
    hipLaunchKernelGGL(fused_din_mfma, grid, block, 0, stream,
                       history, target, hregion, tregion, hvrate,
                       embT, embR, Wq, Wk, Wv, outp);
}

// Round 4
// 309.959 us; speedup vs baseline: 4.5020x; 1.0371x over previous
//
#include <hip/hip_runtime.h>
#include <math.h>

// DIN fused pipeline, round 4: 4 dispatches.
//  P: convert embT/embR/Wk f32 -> bf16 (halves gather bytes, kills in-loop cvt)
//  A: per-batch targ gather + q = Wq*targ (f32), u = Wv^T*targ (bf16), targ_bf16
//  B: per (batch,half): gather 100 hist rows -> swizzled LDS bf16, MFMA vs Wk,
//     scatter faithful-reshape scores into LDS, hdot/tdot vector phase
//  F: sum halves, masked exp, beta=0.5 norm, pred, sigmoid

#define HH 200
#define EE 128

typedef float fp32x4 __attribute__((ext_vector_type(4)));
typedef short bf16x8 __attribute__((ext_vector_type(8)));

static __device__ __forceinline__ unsigned short f2bf(float x) {
    unsigned u = __builtin_bit_cast(unsigned, x);
    unsigned r = (u + 0x7FFFu + ((u >> 16) & 1u)) >> 16;   // RNE
    return (unsigned short)r;
}
static __device__ __forceinline__ float bf2f(unsigned short v) {
    unsigned u = ((unsigned)v) << 16;
    return __builtin_bit_cast(float, u);
}

// ---------------- Kernel P: table conversion ----------------
#define N4_T 1600000   // embT float4 units (100000*64/4)
#define N4_R 16000     // embR
#define N4_K 4096      // Wk
#define N4_ALL (N4_T + N4_R + N4_K)

__global__ __launch_bounds__(256) void convert_tables(
    const float* __restrict__ embT, const float* __restrict__ embR,
    const float* __restrict__ Wk,
    unsigned short* __restrict__ dT, unsigned short* __restrict__ dR,
    unsigned short* __restrict__ dK)
{
    int idx = blockIdx.x * blockDim.x + threadIdx.x;
    int stride = gridDim.x * blockDim.x;
    for (int i = idx; i < N4_ALL; i += stride) {
        const float* src; unsigned short* dst;
        if (i < N4_T)               { src = embT + 4*(size_t)i;            dst = dT + 4*(size_t)i; }
        else if (i < N4_T + N4_R)   { int j = i - N4_T;        src = embR + 4*(size_t)j; dst = dR + 4*(size_t)j; }
        else                        { int j = i - N4_T - N4_R; src = Wk   + 4*(size_t)j; dst = dK + 4*(size_t)j; }
        float4 v = *(const float4*)src;
        ushort4 o;
        o.x = f2bf(v.x); o.y = f2bf(v.y); o.z = f2bf(v.z); o.w = f2bf(v.w);
        *(ushort4*)dst = o;
    }
}

// ---------------- Kernel A: q, u_bf16, targ_bf16 (8 batches/block) ----------------
__global__ __launch_bounds__(256) void proj_qu(
    const int* __restrict__ target, const int* __restrict__ tregion,
    const float* __restrict__ embT, const float* __restrict__ embR,
    const float* __restrict__ Wq, const float* __restrict__ Wv,
    float* __restrict__ qout, unsigned short* __restrict__ ubf,
    unsigned short* __restrict__ tbf)
{
    __shared__ float st[8][128];
    const int tid = threadIdx.x;
    const int b0 = blockIdx.x * 8;

    if (tid < 128) {
        int bb = tid >> 4, j = tid & 15;
        int b = b0 + bb;
        int ti = target[b], ri = tregion[b];
        *(float4*)&st[bb][j*4]      = *(const float4*)(embT + (size_t)ti*64 + j*4);
        *(float4*)&st[bb][64+j*4]   = *(const float4*)(embR + (size_t)ri*64 + j*4);
    }
    __syncthreads();

    if (tid < 128) {
        // q[bb][h=tid] = sum_e Wq[h][e]*targ[e]
        float acc[8] = {0,0,0,0,0,0,0,0};
        const float4* wr = (const float4*)(Wq + (size_t)tid*128);
        for (int e4 = 0; e4 < 32; e4++) {
            float4 w4 = wr[e4];
            #pragma unroll
            for (int bb = 0; bb < 8; bb++) {
                float4 t4 = *(const float4*)&st[bb][e4*4];
                acc[bb] += w4.x*t4.x + w4.y*t4.y + w4.z*t4.z + w4.w*t4.w;
            }
        }
        #pragma unroll
        for (int bb = 0; bb < 8; bb++) qout[(size_t)(b0+bb)*128 + tid] = acc[bb];
    } else {
        // u[e=tid-128] = sum_f targ[f]*Wv[f][e]  (lane-coalesced)
        int e = tid - 128;
        float acc[8] = {0,0,0,0,0,0,0,0};
        for (int f = 0; f < 128; f++) {
            float wv = Wv[(size_t)f*128 + e];
            #pragma unroll
            for (int bb = 0; bb < 8; bb++) acc[bb] += st[bb][f] * wv;
        }
        #pragma unroll
        for (int bb = 0; bb < 8; bb++) ubf[(size_t)(b0+bb)*128 + e] = f2bf(acc[bb]);
    }
    __syncthreads();
    {
        int bb = tid >> 5, x = (tid & 31) * 4;
        float4 t4 = *(const float4*)&st[bb][x];
        ushort4 o; o.x = f2bf(t4.x); o.y = f2bf(t4.y); o.z = f2bf(t4.z); o.w = f2bf(t4.w);
        *(ushort4*)&tbf[(size_t)(b0+bb)*128 + x] = o;
    }
}

// ---------------- Kernel B: hot gather + MFMA + scatter ----------------
// grid 4096: b = bid>>1, hf = bid&1. LDS ~30 KB -> 5 blocks/CU at VGPR<=64.
__global__ __launch_bounds__(256, 8) void hist_gemm(
    const int* __restrict__ history, const int* __restrict__ hregion,
    const unsigned short* __restrict__ eT, const unsigned short* __restrict__ eR,
    const unsigned short* __restrict__ wk, const float* __restrict__ q,
    const unsigned short* __restrict__ ubf, const unsigned short* __restrict__ tbf,
    float* __restrict__ scores_p, float* __restrict__ hdot, float* __restrict__ tdot)
{
    __shared__ unsigned short sh[112*128];   // XOR-swizzled rows of 256 B
    __shared__ float s_q[128];
    __shared__ float s_scores[200];

    const int bid = blockIdx.x;
    const int b = bid >> 1, hf = bid & 1;
    const int tid = threadIdx.x;
    const int lane = tid & 63, w = tid >> 6;
    const int c = lane & 15, e0 = 8*(lane>>4);
    const int rbase = hf * 100;

    // Wk B-fragments resident: wave w owns cols [32w, 32w+32)
    bf16x8 wkf[2][4];
    #pragma unroll
    for (int nt = 0; nt < 2; nt++)
        #pragma unroll
        for (int kc = 0; kc < 4; kc++)
            wkf[nt][kc] = *(const bf16x8*)(wk + (size_t)(32*w + 16*nt + c)*128 + kc*32 + e0);

    if (tid < 32) *(float4*)&s_q[tid*4] = *(const float4*)(q + (size_t)b*128 + tid*4);
    if (tid < 200) s_scores[tid] = 0.f;

    // gather 100 rows, bf16, swizzled 8B writes (16 lanes/row)
    #pragma unroll
    for (int it = 0; it < 7; it++) {
        int r = it*16 + (tid>>4);
        int j = tid & 15;
        if (r < 100) {
            int ih = history[(size_t)b*200 + rbase + r];
            int ir = hregion[(size_t)b*200 + rbase + r];
            unsigned sw = ((unsigned)(r & 7)) << 4;
            unsigned o1 = ((unsigned)(r*256 + j*8)) ^ sw;
            unsigned o2 = ((unsigned)(r*256 + 128 + j*8)) ^ sw;
            *(uint2*)((char*)sh + o1) = *(const uint2*)(eT + (size_t)ih*64 + j*4);
            *(uint2*)((char*)sh + o2) = *(const uint2*)(eR + (size_t)ir*64 + j*4);
        }
    }
    __syncthreads();

    // MFMA + faithful-reshape scatter: scores[f%200] += q[f/200]*k[s,h], f=s*128+h
    for (int mt = 0; mt < 7; mt++) {
        const int ar = mt*16 + c;
        const unsigned swa = ((unsigned)(ar & 7)) << 4;
        bf16x8 a[4];
        #pragma unroll
        for (int kc = 0; kc < 4; kc++) {
            unsigned off = ((unsigned)(ar*256 + kc*64 + e0*2)) ^ swa;
            a[kc] = *(const bf16x8*)((const char*)sh + off);
        }
        fp32x4 acc0 = {0,0,0,0}, acc1 = {0,0,0,0};
        #pragma unroll
        for (int kc = 0; kc < 4; kc++) {
            acc0 = __builtin_amdgcn_mfma_f32_16x16x32_bf16(a[kc], wkf[0][kc], acc0, 0, 0, 0);
            acc1 = __builtin_amdgcn_mfma_f32_16x16x32_bf16(a[kc], wkf[1][kc], acc1, 0, 0, 0);
        }
        const int slb = mt*16 + 4*(lane>>4);
        #pragma unroll
        for (int r = 0; r < 4; r++) {
            int sl = slb + r;
            if (sl < 100) {
                unsigned f  = (unsigned)((rbase + sl)*128 + 32*w + c);
                unsigned fd = f / 200u, fm = f - fd*200u;
                atomicAdd(&s_scores[fm], s_q[fd] * acc0[r]);
                unsigned f2  = f + 16u;
                unsigned fd2 = f2 / 200u, fm2 = f2 - fd2*200u;
                atomicAdd(&s_scores[fm2], s_q[fd2] * acc1[r]);
            }
        }
    }

    // hdot/tdot: 2 threads per row, b128 LDS reads, pair-reduce, direct store
    if (tid < 200) {
        int r = tid >> 1, hc = tid & 1;
        float hd = 0.f, td = 0.f;
        const unsigned short* up = ubf + (size_t)b*128 + hc*64;
        const unsigned short* tp = tbf + (size_t)b*128 + hc*64;
        const unsigned swr = ((unsigned)(r & 7)) << 4;
        #pragma unroll
        for (int cc = 0; cc < 8; cc++) {
            unsigned off = ((unsigned)(r*256 + hc*128 + cc*16)) ^ swr;
            bf16x8 hv = *(const bf16x8*)((const char*)sh + off);
            bf16x8 uv = *(const bf16x8*)(up + cc*8);
            bf16x8 tv = *(const bf16x8*)(tp + cc*8);
            #pragma unroll
            for (int k = 0; k < 8; k++) {
                float hfv = bf2f((unsigned short)hv[k]);
                hd += hfv * bf2f((unsigned short)uv[k]);
                td += hfv * bf2f((unsigned short)tv[k]);
            }
        }
        hd += __shfl_xor(hd, 1, 64);
        td += __shfl_xor(td, 1, 64);
        if (hc == 0) {
            hdot[(size_t)b*200 + rbase + r] = hd;
            tdot[(size_t)b*200 + rbase + r] = td;
        }
    }
    __syncthreads();
    if (tid < 200) scores_p[(size_t)bid*200 + tid] = s_scores[tid];
}

// ---------------- Kernel F: finalize (8 batches/block, 1 wave = 1 batch x2) ----------------
__global__ __launch_bounds__(256) void finalize_k(
    const int* __restrict__ history, const int* __restrict__ target,
    const float* __restrict__ hvr,
    const float* __restrict__ scores_p, const float* __restrict__ hdot,
    const float* __restrict__ tdot, float* __restrict__ out)
{
    const int tid = threadIdx.x, lane = tid & 63, w = tid >> 6;
    #pragma unroll
    for (int bb = 0; bb < 2; bb++) {
        int b = blockIdx.x*8 + w*2 + bb;
        int tgt = target[b];
        float ev[4], hd[4], td[4], hv[4];
        #pragma unroll
        for (int i = 0; i < 4; i++) {
            int j = lane + i*64;
            if (j < 200) {
                float sc = scores_p[(size_t)(2*b)*200 + j] + scores_p[(size_t)(2*b+1)*200 + j];
                int uh = history[(size_t)b*200 + j];
                ev[i] = (uh != tgt) ? expf(sc * 0.088388347648318447f) : 0.f;
                hd[i] = hdot[(size_t)b*200 + j];
                td[i] = tdot[(size_t)b*200 + j];
                hv[i] = hvr[j];
            } else { ev[i] = 0.f; hd[i] = 0.f; td[i] = 0.f; hv[i] = 0.f; }
        }
        float tot = (ev[0]+ev[1]) + (ev[2]+ev[3]);
        #pragma unroll
        for (int m = 1; m < 64; m <<= 1) tot += __shfl_xor(tot, m, 64);
        float inv = rsqrtf(tot);          // exp_A / sum^0.5
        float p = 0.f;
        #pragma unroll
        for (int i = 0; i < 4; i++) p += ev[i]*inv*hd[i] + hv[i]*td[i];
        #pragma unroll
        for (int m = 1; m < 64; m <<= 1) p += __shfl_xor(p, m, 64);
        if (lane == 0) out[b] = 1.0f / (1.0f + expf(-p));
    }
}

extern "C" void kernel_launch(void* const* d_in, const int* in_sizes, int n_in,
                              void* d_out, int out_size, void* d_ws, size_t ws_size,
                              hipStream_t stream) {
    const int*   history = (const int*)d_in[0];
    const int*   target  = (const int*)d_in[1];
    const int*   hregion = (const int*)d_in[2];
    const int*   tregion = (const int*)d_in[3];
    const float* hvrate  = (const float*)d_in[4];
    const float* embT    = (const float*)d_in[5];
    const float* embR    = (const float*)d_in[6];
    const float* Wq      = (const float*)d_in[7];
    const float* Wk      = (const float*)d_in[8];
    const float* Wv      = (const float*)d_in[9];
    float* outp = (float*)d_out;

    char* ws = (char*)d_ws;
    unsigned short* dT = (unsigned short*)(ws);                 // 12,800,000 B
    unsigned short* dR = (unsigned short*)(ws + 12800000);      //    128,000
    unsigned short* dK = (unsigned short*)(ws + 12928000);      //     32,768
    unsigned short* ub = (unsigned short*)(ws + 12960768);      //    524,288
    unsigned short* tb = (unsigned short*)(ws + 13485056);      //    524,288
    float* qbuf        = (float*)(ws + 14009344);               //  1,048,576
    float* sp          = (float*)(ws + 15057920);               //  3,276,800
    float* hdp         = (float*)(ws + 18334720);               //  1,638,400
    float* tdp         = (float*)(ws + 19973120);               //  1,638,400  (end 21,611,520)

    hipLaunchKernelGGL(convert_tables, dim3(2048), dim3(256), 0, stream,
                       embT, embR, Wk, dT, dR, dK);
    hipLaunchKernelGGL(proj_qu, dim3(256), dim3(256), 0, stream,
                       target, tregion, embT, embR, Wq, Wv, qbuf, ub, tb);
    hipLaunchKernelGGL(hist_gemm, dim3(4096), dim3(256), 0, stream,
                       history, hregion, dT, dR, dK, qbuf, ub, tb, sp, hdp, tdp);
    hipLaunchKernelGGL(finalize_k, dim3(256), dim3(256), 0, stream,
                       history, target, hvrate, sp, hdp, tdp, outp);
}

// Round 5
// 87.204 us; speedup vs baseline: 16.0018x; 3.5544x over previous
//
#include <hip/hip_runtime.h>
#include <math.h>

// DIN fused pipeline, round 5: kill LDS atomics in kernel B.
//  P: convert embT/embR/Wk f32 -> bf16
//  A: per-batch targ gather + q = Wq*targ (f32), u = Wv^T*targ (bf16), targ_bf16
//  B: per (batch,half): gather 100 hist rows -> swizzled LDS bf16, MFMA vs Wk,
//     scatter faithful-reshape scores into WAVE-PRIVATE LDS buffers (plain RMW,
//     race-free: within one scatter instr all 64 lanes hit distinct f%200),
//     hdot/tdot vector phase, 4-way cross-wave score reduce.
//  F: sum halves, masked exp, beta=0.5 norm, pred, sigmoid

#define HH 200
#define EE 128

typedef float fp32x4 __attribute__((ext_vector_type(4)));
typedef short bf16x8 __attribute__((ext_vector_type(8)));

static __device__ __forceinline__ unsigned short f2bf(float x) {
    unsigned u = __builtin_bit_cast(unsigned, x);
    unsigned r = (u + 0x7FFFu + ((u >> 16) & 1u)) >> 16;   // RNE
    return (unsigned short)r;
}
static __device__ __forceinline__ float bf2f(unsigned short v) {
    unsigned u = ((unsigned)v) << 16;
    return __builtin_bit_cast(float, u);
}

// ---------------- Kernel P: table conversion ----------------
#define N4_T 1600000   // embT float4 units (100000*64/4)
#define N4_R 16000     // embR
#define N4_K 4096      // Wk
#define N4_ALL (N4_T + N4_R + N4_K)

__global__ __launch_bounds__(256) void convert_tables(
    const float* __restrict__ embT, const float* __restrict__ embR,
    const float* __restrict__ Wk,
    unsigned short* __restrict__ dT, unsigned short* __restrict__ dR,
    unsigned short* __restrict__ dK)
{
    int idx = blockIdx.x * blockDim.x + threadIdx.x;
    int stride = gridDim.x * blockDim.x;
    for (int i = idx; i < N4_ALL; i += stride) {
        const float* src; unsigned short* dst;
        if (i < N4_T)               { src = embT + 4*(size_t)i;            dst = dT + 4*(size_t)i; }
        else if (i < N4_T + N4_R)   { int j = i - N4_T;        src = embR + 4*(size_t)j; dst = dR + 4*(size_t)j; }
        else                        { int j = i - N4_T - N4_R; src = Wk   + 4*(size_t)j; dst = dK + 4*(size_t)j; }
        float4 v = *(const float4*)src;
        ushort4 o;
        o.x = f2bf(v.x); o.y = f2bf(v.y); o.z = f2bf(v.z); o.w = f2bf(v.w);
        *(ushort4*)dst = o;
    }
}

// ---------------- Kernel A: q, u_bf16, targ_bf16 (8 batches/block) ----------------
__global__ __launch_bounds__(256) void proj_qu(
    const int* __restrict__ target, const int* __restrict__ tregion,
    const float* __restrict__ embT, const float* __restrict__ embR,
    const float* __restrict__ Wq, const float* __restrict__ Wv,
    float* __restrict__ qout, unsigned short* __restrict__ ubf,
    unsigned short* __restrict__ tbf)
{
    __shared__ float st[8][128];
    const int tid = threadIdx.x;
    const int b0 = blockIdx.x * 8;

    if (tid < 128) {
        int bb = tid >> 4, j = tid & 15;
        int b = b0 + bb;
        int ti = target[b], ri = tregion[b];
        *(float4*)&st[bb][j*4]      = *(const float4*)(embT + (size_t)ti*64 + j*4);
        *(float4*)&st[bb][64+j*4]   = *(const float4*)(embR + (size_t)ri*64 + j*4);
    }
    __syncthreads();

    if (tid < 128) {
        float acc[8] = {0,0,0,0,0,0,0,0};
        const float4* wr = (const float4*)(Wq + (size_t)tid*128);
        for (int e4 = 0; e4 < 32; e4++) {
            float4 w4 = wr[e4];
            #pragma unroll
            for (int bb = 0; bb < 8; bb++) {
                float4 t4 = *(const float4*)&st[bb][e4*4];
                acc[bb] += w4.x*t4.x + w4.y*t4.y + w4.z*t4.z + w4.w*t4.w;
            }
        }
        #pragma unroll
        for (int bb = 0; bb < 8; bb++) qout[(size_t)(b0+bb)*128 + tid] = acc[bb];
    } else {
        int e = tid - 128;
        float acc[8] = {0,0,0,0,0,0,0,0};
        for (int f = 0; f < 128; f++) {
            float wv = Wv[(size_t)f*128 + e];
            #pragma unroll
            for (int bb = 0; bb < 8; bb++) acc[bb] += st[bb][f] * wv;
        }
        #pragma unroll
        for (int bb = 0; bb < 8; bb++) ubf[(size_t)(b0+bb)*128 + e] = f2bf(acc[bb]);
    }
    __syncthreads();
    {
        int bb = tid >> 5, x = (tid & 31) * 4;
        float4 t4 = *(const float4*)&st[bb][x];
        ushort4 o; o.x = f2bf(t4.x); o.y = f2bf(t4.y); o.z = f2bf(t4.z); o.w = f2bf(t4.w);
        *(ushort4*)&tbf[(size_t)(b0+bb)*128 + x] = o;
    }
}

// ---------------- Kernel B: hot gather + MFMA + scatter (no atomics) ----------------
// grid 4096: b = bid>>1, hf = bid&1. LDS ~29.3 KB -> 5 blocks/CU.
__global__ __launch_bounds__(256, 8) void hist_gemm(
    const int* __restrict__ history, const int* __restrict__ hregion,
    const unsigned short* __restrict__ eT, const unsigned short* __restrict__ eR,
    const unsigned short* __restrict__ wk, const float* __restrict__ q,
    const unsigned short* __restrict__ ubf, const unsigned short* __restrict__ tbf,
    float* __restrict__ scores_p, float* __restrict__ hdot, float* __restrict__ tdot)
{
    __shared__ unsigned short sh[100*128];   // XOR-swizzled rows of 256 B
    __shared__ float s_q[128];
    __shared__ float s_wscore[4][200];       // wave-private score accumulators

    const int bid = blockIdx.x;
    const int b = bid >> 1, hf = bid & 1;
    const int tid = threadIdx.x;
    const int lane = tid & 63, w = tid >> 6;
    const int c = lane & 15, e0 = 8*(lane>>4);
    const int rbase = hf * 100;

    // Wk B-fragments resident: wave w owns cols [32w, 32w+32)
    bf16x8 wkf[2][4];
    #pragma unroll
    for (int nt = 0; nt < 2; nt++)
        #pragma unroll
        for (int kc = 0; kc < 4; kc++)
            wkf[nt][kc] = *(const bf16x8*)(wk + (size_t)(32*w + 16*nt + c)*128 + kc*32 + e0);

    if (tid < 32) *(float4*)&s_q[tid*4] = *(const float4*)(q + (size_t)b*128 + tid*4);
    for (int i = tid; i < 800; i += 256) ((float*)s_wscore)[i] = 0.f;

    // gather 100 rows, bf16, swizzled 8B writes (16 lanes/row)
    #pragma unroll
    for (int it = 0; it < 7; it++) {
        int r = it*16 + (tid>>4);
        int j = tid & 15;
        if (r < 100) {
            int ih = history[(size_t)b*200 + rbase + r];
            int ir = hregion[(size_t)b*200 + rbase + r];
            unsigned sw = ((unsigned)(r & 7)) << 4;
            unsigned o1 = ((unsigned)(r*256 + j*8)) ^ sw;
            unsigned o2 = ((unsigned)(r*256 + 128 + j*8)) ^ sw;
            *(uint2*)((char*)sh + o1) = *(const uint2*)(eT + (size_t)ih*64 + j*4);
            *(uint2*)((char*)sh + o2) = *(const uint2*)(eR + (size_t)ir*64 + j*4);
        }
    }
    __syncthreads();

    // MFMA + faithful-reshape scatter into wave-private buffer:
    //   scores[f%200] += q[f/200]*k[s,h], f=(rbase+s)*128+h
    // mt 0..5 cover rows 0..95; mt 6 re-reads rows 84..99, scatters sl>=96 only.
    float* wsc = s_wscore[w];
    #pragma unroll 1
    for (int mt = 0; mt < 7; mt++) {
        const int r0 = (mt < 6) ? mt*16 : 84;
        const int ar = r0 + c;
        const unsigned swa = ((unsigned)(ar & 7)) << 4;
        bf16x8 a[4];
        #pragma unroll
        for (int kc = 0; kc < 4; kc++) {
            unsigned off = ((unsigned)(ar*256 + kc*64 + e0*2)) ^ swa;
            a[kc] = *(const bf16x8*)((const char*)sh + off);
        }
        fp32x4 acc0 = {0,0,0,0}, acc1 = {0,0,0,0};
        #pragma unroll
        for (int kc = 0; kc < 4; kc++) {
            acc0 = __builtin_amdgcn_mfma_f32_16x16x32_bf16(a[kc], wkf[0][kc], acc0, 0, 0, 0);
            acc1 = __builtin_amdgcn_mfma_f32_16x16x32_bf16(a[kc], wkf[1][kc], acc1, 0, 0, 0);
        }
        const int slb = r0 + 4*(lane>>4);
        #pragma unroll
        for (int r = 0; r < 4; r++) {
            int sl = slb + r;
            if (mt < 6 || sl >= 96) {
                unsigned f  = (unsigned)((rbase + sl)*128 + 32*w + c);
                unsigned fd = f / 200u, fm = f - fd*200u;
                wsc[fm] += s_q[fd] * acc0[r];
                unsigned f2  = f + 16u;
                unsigned fd2 = f2 / 200u, fm2 = f2 - fd2*200u;
                wsc[fm2] += s_q[fd2] * acc1[r];
            }
        }
    }

    // hdot/tdot: 2 threads per row, b128 LDS reads, pair-reduce, direct store
    if (tid < 200) {
        int r = tid >> 1, hc = tid & 1;
        float hd = 0.f, td = 0.f;
        const unsigned short* up = ubf + (size_t)b*128 + hc*64;
        const unsigned short* tp = tbf + (size_t)b*128 + hc*64;
        const unsigned swr = ((unsigned)(r & 7)) << 4;
        #pragma unroll
        for (int cc = 0; cc < 8; cc++) {
            unsigned off = ((unsigned)(r*256 + hc*128 + cc*16)) ^ swr;
            bf16x8 hv = *(const bf16x8*)((const char*)sh + off);
            bf16x8 uv = *(const bf16x8*)(up + cc*8);
            bf16x8 tv = *(const bf16x8*)(tp + cc*8);
            #pragma unroll
            for (int k = 0; k < 8; k++) {
                float hfv = bf2f((unsigned short)hv[k]);
                hd += hfv * bf2f((unsigned short)uv[k]);
                td += hfv * bf2f((unsigned short)tv[k]);
            }
        }
        hd += __shfl_xor(hd, 1, 64);
        td += __shfl_xor(td, 1, 64);
        if (hc == 0) {
            hdot[(size_t)b*200 + rbase + r] = hd;
            tdot[(size_t)b*200 + rbase + r] = td;
        }
    }
    __syncthreads();

    // cross-wave score reduce + writeout (lanes consecutive -> conflict-free)
    if (tid < 200) {
        float s = (s_wscore[0][tid] + s_wscore[1][tid])
                + (s_wscore[2][tid] + s_wscore[3][tid]);
        scores_p[(size_t)bid*200 + tid] = s;
    }
}

// ---------------- Kernel F: finalize (8 batches/block) ----------------
__global__ __launch_bounds__(256) void finalize_k(
    const int* __restrict__ history, const int* __restrict__ target,
    const float* __restrict__ hvr,
    const float* __restrict__ scores_p, const float* __restrict__ hdot,
    const float* __restrict__ tdot, float* __restrict__ out)
{
    const int tid = threadIdx.x, lane = tid & 63, w = tid >> 6;
    #pragma unroll
    for (int bb = 0; bb < 2; bb++) {
        int b = blockIdx.x*8 + w*2 + bb;
        int tgt = target[b];
        float ev[4], hd[4], td[4], hv[4];
        #pragma unroll
        for (int i = 0; i < 4; i++) {
            int j = lane + i*64;
            if (j < 200) {
                float sc = scores_p[(size_t)(2*b)*200 + j] + scores_p[(size_t)(2*b+1)*200 + j];
                int uh = history[(size_t)b*200 + j];
                ev[i] = (uh != tgt) ? expf(sc * 0.088388347648318447f) : 0.f;
                hd[i] = hdot[(size_t)b*200 + j];
                td[i] = tdot[(size_t)b*200 + j];
                hv[i] = hvr[j];
            } else { ev[i] = 0.f; hd[i] = 0.f; td[i] = 0.f; hv[i] = 0.f; }
        }
        float tot = (ev[0]+ev[1]) + (ev[2]+ev[3]);
        #pragma unroll
        for (int m = 1; m < 64; m <<= 1) tot += __shfl_xor(tot, m, 64);
        float inv = rsqrtf(tot);          // exp_A / sum^0.5
        float p = 0.f;
        #pragma unroll
        for (int i = 0; i < 4; i++) p += ev[i]*inv*hd[i] + hv[i]*td[i];
        #pragma unroll
        for (int m = 1; m < 64; m <<= 1) p += __shfl_xor(p, m, 64);
        if (lane == 0) out[b] = 1.0f / (1.0f + expf(-p));
    }
}

extern "C" void kernel_launch(void* const* d_in, const int* in_sizes, int n_in,
                              void* d_out, int out_size, void* d_ws, size_t ws_size,
                              hipStream_t stream) {
    const int*   history = (const int*)d_in[0];
    const int*   target  = (const int*)d_in[1];
    const int*   hregion = (const int*)d_in[2];
    const int*   tregion = (const int*)d_in[3];
    const float* hvrate  = (const float*)d_in[4];
    const float* embT    = (const float*)d_in[5];
    const float* embR    = (const float*)d_in[6];
    const float* Wq      = (const float*)d_in[7];
    const float* Wk      = (const float*)d_in[8];
    const float* Wv      = (const float*)d_in[9];
    float* outp = (float*)d_out;

    char* ws = (char*)d_ws;
    unsigned short* dT = (unsigned short*)(ws);                 // 12,800,000 B
    unsigned short* dR = (unsigned short*)(ws + 12800000);      //    128,000
    unsigned short* dK = (unsigned short*)(ws + 12928000);      //     32,768
    unsigned short* ub = (unsigned short*)(ws + 12960768);      //    524,288
    unsigned short* tb = (unsigned short*)(ws + 13485056);      //    524,288
    float* qbuf        = (float*)(ws + 14009344);               //  1,048,576
    float* sp          = (float*)(ws + 15057920);               //  3,276,800
    float* hdp         = (float*)(ws + 18334720);               //  1,638,400
    float* tdp         = (float*)(ws + 19973120);               //  1,638,400  (end 21,611,520)

    hipLaunchKernelGGL(convert_tables, dim3(2048), dim3(256), 0, stream,
                       embT, embR, Wk, dT, dR, dK);
    hipLaunchKernelGGL(proj_qu, dim3(256), dim3(256), 0, stream,
                       target, tregion, embT, embR, Wq, Wv, qbuf, ub, tb);
    hipLaunchKernelGGL(hist_gemm, dim3(4096), dim3(256), 0, stream,
                       history, hregion, dT, dR, dK, qbuf, ub, tb, sp, hdp, tdp);
    hipLaunchKernelGGL(finalize_k, dim3(256), dim3(256), 0, stream,
                       history, target, hvrate, sp, hdp, tdp, outp);
}